// Round 9
// baseline (446.211 us; speedup 1.0000x reference)
//
#include <hip/hip_runtime.h>
#include <hip/hip_bf16.h>
#include <hip/hip_cooperative_groups.h>
#include <math.h>

namespace cg = cooperative_groups;

#define BB 8
#define NN 1024
#define DIM 768
#define HEADS 12
#define CR 384
#define HD 32
#define MROWS (BB*NN)   // 8192
#define EPS 1e-5f
#define SCALE_Q 0.25503486f   // (1/sqrt(32)) * log2(e): P = exp2(s) directly

typedef __attribute__((ext_vector_type(8))) __bf16 bf16x8;
typedef __attribute__((ext_vector_type(8))) unsigned short u16x8;
typedef __attribute__((ext_vector_type(4))) float f32x4;

__device__ __forceinline__ unsigned short f2bf(float f) {
    unsigned int u = __float_as_uint(f);
    u += 0x7fffu + ((u >> 16) & 1u);   // RNE; finite inputs only
    return (unsigned short)(u >> 16);
}

__device__ __forceinline__ unsigned int packbf2(float lo, float hi) {
    __hip_bfloat162 h2 = __float22bfloat162_rn(make_float2(lo, hi));
    unsigned int u; __builtin_memcpy(&u, &h2, sizeof(u));
    return u;
}

// async global->LDS, 16B/lane; LDS dest = wave-uniform base + lane*16
__device__ __forceinline__ void async_cp16(const unsigned short* g, unsigned short* l) {
    __builtin_amdgcn_global_load_lds(
        (const __attribute__((address_space(1))) unsigned int*)g,
        (__attribute__((address_space(3))) unsigned int*)l, 16, 0, 0);
}

// ================= shared device tile routines (R7-proven) =================

// 128x128 bf16 MFMA GEMM tile, dbuf LDS + prefetch.
// MODE 0: f32 out (pitch CR, no bias) -> C0
// MODE 1: qkv epilogue: cols<384 -> bf16 q*SCALE_Q into C0 pitch 768; 384..767 -> bf16 k;
//         cols>=768 -> V^T bf16 into C1 [ch][token] pitch 8192.
template<int KD, int NITER, int MODE>
__device__ void gemm_tile(const unsigned short* __restrict__ A,
                          const unsigned short* __restrict__ W,
                          int m0, int n0, int koff,
                          unsigned short* Asm, unsigned short* Bsm,
                          void* C0, void* C1)
{
    const int t = threadIdx.x;
    const int wave = t >> 6, lane = t & 63;
    const int l15 = lane & 15, quad = lane >> 4;
    const int wm = (wave & 1) * 64, wn = (wave >> 1) * 64;
    const int srow = lane >> 2;
    const int skq  = (lane & 3) * 8;
    const unsigned short* gA = A + (size_t)(m0 + wave * 32 + srow) * KD + koff + skq;
    const unsigned short* gB = W + (size_t)(n0 + wave * 32 + srow) * KD + koff + skq;
    unsigned short* lA = Asm + wave * 1024;
    unsigned short* lB = Bsm + wave * 1024;

    async_cp16(gA, lA);
    async_cp16(gA + (size_t)16 * KD, lA + 512);
    async_cp16(gB, lB);
    async_cp16(gB + (size_t)16 * KD, lB + 512);

    f32x4 acc[4][4];
#pragma unroll
    for (int i = 0; i < 4; i++)
#pragma unroll
        for (int j = 0; j < 4; j++) acc[i][j] = (f32x4){0.f, 0.f, 0.f, 0.f};

    for (int it = 0; it < NITER; it++) {
        __syncthreads();
        const int cur = it & 1;
        if (it + 1 < NITER) {
            const int noff = (cur ^ 1) * 4096;
            async_cp16(gA + (it + 1) * 32, lA + noff);
            async_cp16(gA + (size_t)16 * KD + (it + 1) * 32, lA + noff + 512);
            async_cp16(gB + (it + 1) * 32, lB + noff);
            async_cp16(gB + (size_t)16 * KD + (it + 1) * 32, lB + noff + 512);
        }
        const unsigned short* Ab = Asm + cur * 4096;
        const unsigned short* Bb = Bsm + cur * 4096;
        bf16x8 af[4], bfr[4];
#pragma unroll
        for (int i = 0; i < 4; i++)
            af[i] = *(const bf16x8*)(Ab + (wm + i * 16 + l15) * 32 + quad * 8);
#pragma unroll
        for (int j = 0; j < 4; j++)
            bfr[j] = *(const bf16x8*)(Bb + (wn + j * 16 + l15) * 32 + quad * 8);
#pragma unroll
        for (int i = 0; i < 4; i++)
#pragma unroll
            for (int j = 0; j < 4; j++)
                acc[i][j] = __builtin_amdgcn_mfma_f32_16x16x32_bf16(af[i], bfr[j], acc[i][j], 0, 0, 0);
    }
    __syncthreads();   // LDS reads done before caller reuses buffers

    if constexpr (MODE == 0) {
        float* C = (float*)C0;
#pragma unroll
        for (int i = 0; i < 4; i++)
#pragma unroll
            for (int j = 0; j < 4; j++)
#pragma unroll
                for (int reg = 0; reg < 4; reg++) {
                    int row = m0 + wm + i * 16 + quad * 4 + reg;
                    int col = n0 + wn + j * 16 + l15;
                    C[(size_t)row * CR + col] = acc[i][j][reg];
                }
    } else {
        unsigned short* Cqk = (unsigned short*)C0;
        unsigned short* Vt  = (unsigned short*)C1;
#pragma unroll
        for (int i = 0; i < 4; i++)
#pragma unroll
            for (int j = 0; j < 4; j++) {
                const int colbase = n0 + wn + j * 16;
                const int token0 = m0 + wm + i * 16 + quad * 4;
                if (colbase < DIM) {
                    const float sc = (colbase < CR) ? SCALE_Q : 1.f;
#pragma unroll
                    for (int reg = 0; reg < 4; reg++)
                        Cqk[(size_t)(token0 + reg) * DIM + colbase + l15] = f2bf(acc[i][j][reg] * sc);
                } else {
                    const int ch = colbase - DIM + l15;
                    uint2 pk;
                    pk.x = packbf2(acc[i][j][0], acc[i][j][1]);
                    pk.y = packbf2(acc[i][j][2], acc[i][j][3]);
                    *(uint2*)(Vt + (size_t)ch * MROWS + token0) = pk;
                }
            }
    }
}

// attention tile: 128 q x 1 head, S^T core
__device__ void attn_tile(int qt, int bh,
                          const unsigned short* __restrict__ qk,
                          const unsigned short* __restrict__ vt,
                          const float* __restrict__ h, float* __restrict__ out,
                          unsigned short* Ks, unsigned short* Vs, unsigned short* PsBase)
{
    const int b = bh / HEADS, head = bh % HEADS;
    const int hc = head * HD;
    const int t = threadIdx.x;
    const int wave = t >> 6, lane = t & 63;
    const int l15 = lane & 15, quad = lane >> 4;
    const int q0 = qt * 128;
    unsigned short* Pw = PsBase + wave * (32 * 72);

    bf16x8 qa[2];
#pragma unroll
    for (int qi = 0; qi < 2; qi++)
        qa[qi] = *(const bf16x8*)(qk + (size_t)(b * NN + q0 + wave * 32 + qi * 16 + l15) * DIM
                                  + hc + quad * 8);

    const int rr = t >> 2, seg = t & 3;
    const unsigned short* gK = qk + (size_t)(b * NN + rr) * DIM + CR + hc + seg * 8;
    const int vch = wave * 8 + (lane >> 3), vko = (lane & 7) * 8;
    const unsigned short* gV = vt + (size_t)(hc + vch) * MROWS + b * NN + vko;

    u16x8 kreg = *(const u16x8*)gK;
    u16x8 vreg = *(const u16x8*)gV;

    f32x4 o[2][2] = {{{0.f,0.f,0.f,0.f},{0.f,0.f,0.f,0.f}},
                     {{0.f,0.f,0.f,0.f},{0.f,0.f,0.f,0.f}}};
    float lpart[2] = {0.f, 0.f};

    for (int kt = 0; kt < 16; kt++) {
        __syncthreads();
        *(u16x8*)(Ks + rr * 40 + seg * 8) = kreg;
        *(u16x8*)(Vs + vch * 72 + vko) = vreg;
        if (kt < 15) {
            kreg = *(const u16x8*)(gK + (size_t)(kt + 1) * 64 * DIM);
            vreg = *(const u16x8*)(gV + (kt + 1) * 64);
        }
        __syncthreads();

        bf16x8 kb[4];
#pragma unroll
        for (int nt = 0; nt < 4; nt++)
            kb[nt] = *(const bf16x8*)(Ks + (nt * 16 + l15) * 40 + quad * 8);

#pragma unroll
        for (int qi = 0; qi < 2; qi++) {
            f32x4 s[4];
#pragma unroll
            for (int nt = 0; nt < 4; nt++) {
                f32x4 z = {0.f, 0.f, 0.f, 0.f};
                s[nt] = __builtin_amdgcn_mfma_f32_16x16x32_bf16(kb[nt], qa[qi], z, 0, 0, 0);
            }
#pragma unroll
            for (int nt = 0; nt < 4; nt++) {
                float e0 = __builtin_amdgcn_exp2f(s[nt][0]);
                float e1 = __builtin_amdgcn_exp2f(s[nt][1]);
                float e2 = __builtin_amdgcn_exp2f(s[nt][2]);
                float e3 = __builtin_amdgcn_exp2f(s[nt][3]);
                lpart[qi] += (e0 + e1) + (e2 + e3);
                uint2 pk;
                pk.x = packbf2(e0, e1);
                pk.y = packbf2(e2, e3);
                *(uint2*)(Pw + (qi * 16 + l15) * 72 + nt * 16 + quad * 4) = pk;
            }
        }

        bf16x8 vb[2][2];
#pragma unroll
        for (int kk = 0; kk < 2; kk++)
#pragma unroll
            for (int nt2 = 0; nt2 < 2; nt2++)
                vb[kk][nt2] = *(const bf16x8*)(Vs + (nt2 * 16 + l15) * 72 + kk * 32 + quad * 8);

#pragma unroll
        for (int qi = 0; qi < 2; qi++)
#pragma unroll
            for (int kk = 0; kk < 2; kk++) {
                bf16x8 pa = *(const bf16x8*)(Pw + (qi * 16 + l15) * 72 + kk * 32 + quad * 8);
#pragma unroll
                for (int nt2 = 0; nt2 < 2; nt2++)
                    o[qi][nt2] = __builtin_amdgcn_mfma_f32_16x16x32_bf16(pa, vb[kk][nt2], o[qi][nt2], 0, 0, 0);
            }
    }
    __syncthreads();   // protect LDS before next job reuses it

#pragma unroll
    for (int qi = 0; qi < 2; qi++) {
        float l = lpart[qi];
        l += __shfl_xor(l, 16, 64);
        l += __shfl_xor(l, 32, 64);
        const float linv = 1.f / l;
#pragma unroll
        for (int reg = 0; reg < 4; reg++) {
            const float li = __shfl(linv, quad * 4 + reg, 64);
            const size_t row = (size_t)(b * NN + q0 + wave * 32 + qi * 16 + quad * 4 + reg);
#pragma unroll
            for (int nt2 = 0; nt2 < 2; nt2++) {
                size_t idx = row * CR + hc + nt2 * 16 + l15;
                out[idx] = h[idx] + o[qi][nt2][reg] * li;
            }
        }
    }
}

// phase-overlaid LDS (32 KB max)
union Smem {
    struct { unsigned short A[2 * 128 * 32]; unsigned short B[2 * 128 * 32]; } g;  // 32 KB
    struct { unsigned short Ks[64 * 40]; unsigned short Vs[32 * 72];
             unsigned short Ps[4 * 32 * 72]; } at;                                  // 28.2 KB
};

// ================= the megakernel: 5 phases, 4 grid syncs, grid-stride =================
__global__ __launch_bounds__(256, 2) void fused_all(
    const float* __restrict__ x,
    const float* __restrict__ ln0_g, const float* __restrict__ ln0_b,
    const float* __restrict__ w_proj, const float* __restrict__ b_proj,
    const float* __restrict__ ln1_g, const float* __restrict__ ln1_b,
    const float* __restrict__ wq, const float* __restrict__ wk,
    const float* __restrict__ wv,
    unsigned short* a0, unsigned short* wp, unsigned short* wqkv,
    float* hp, float* hbuf, unsigned short* yb,
    unsigned short* qkb, unsigned short* vtb, float* out, int nblk)
{
    __shared__ Smem sm;
    cg::grid_group grid = cg::this_grid();
    const int bid = blockIdx.x;
    const int t = threadIdx.x;
    const int wave = t >> 6, lane = t & 63;

    // ---- P0: LN0 (wave-per-row, no barriers) + weight casts ----
#pragma unroll 1
    for (int row = bid * 4 + wave; row < MROWS; row += nblk * 4) {
        const float* a = x + (size_t)row * DIM;
        float4 v[3]; float s = 0.f, ss = 0.f;
#pragma unroll
        for (int c = 0; c < 3; c++) {
            v[c] = ((const float4*)a)[lane + c * 64];
            s  += v[c].x + v[c].y + v[c].z + v[c].w;
            ss += v[c].x * v[c].x + v[c].y * v[c].y + v[c].z * v[c].z + v[c].w * v[c].w;
        }
#pragma unroll
        for (int off = 1; off < 64; off <<= 1) {
            s += __shfl_xor(s, off, 64); ss += __shfl_xor(ss, off, 64);
        }
        const float mu = s / DIM, rs = rsqrtf(ss / DIM - mu * mu + EPS);
#pragma unroll
        for (int c = 0; c < 3; c++) {
            float4 gv = ((const float4*)ln0_g)[lane + c * 64];
            float4 bv = ((const float4*)ln0_b)[lane + c * 64];
            uint2 pk;
            pk.x = packbf2((v[c].x - mu) * rs * gv.x + bv.x, (v[c].y - mu) * rs * gv.y + bv.y);
            pk.y = packbf2((v[c].z - mu) * rs * gv.z + bv.z, (v[c].w - mu) * rs * gv.w + bv.w);
            *(uint2*)(a0 + (size_t)row * DIM + (lane + c * 64) * 4) = pk;
        }
    }
#pragma unroll 1
    for (int i = bid * 256 + t; i < 184320; i += nblk * 256) {
        const float* src; unsigned short* dst; int off;
        if (i < 73728) { src = w_proj; dst = wp; off = i; }
        else {
            int j = i - 73728;
            int sel = j / 36864; off = j % 36864;
            src = sel == 0 ? wq : (sel == 1 ? wk : wv);
            dst = wqkv + (size_t)sel * 147456;
        }
        float4 v = ((const float4*)src)[off];
        uint2 pk; pk.x = packbf2(v.x, v.y); pk.y = packbf2(v.z, v.w);
        ((uint2*)dst)[off] = pk;
    }
    __threadfence(); grid.sync();

    // ---- P1: gemm1 split-K2: hp[z] = a0 @ wp^T (K-half z), 384 jobs ----
#pragma unroll 1
    for (int job = bid; job < 384; job += nblk) {
        const int n0 = (job % 3) * 128;
        const int m0 = ((job / 3) & 63) * 128;
        const int z  = job / 192;
        gemm_tile<DIM, 12, 0>(a0, wp, m0, n0, z * 384, sm.g.A, sm.g.B,
                              hp + (size_t)z * MROWS * CR, nullptr);
    }
    __threadfence(); grid.sync();

    // ---- P2: ln1 (wave-per-row): hs = hp0+hp1+bias; y = bf16(LN1(hs)) ----
    {
        const float* h1 = hp + (size_t)MROWS * CR;
#pragma unroll 1
        for (int row = bid * 4 + wave; row < MROWS; row += nblk * 4) {
            float4 c0 = make_float4(0.f,0.f,0.f,0.f), c1 = make_float4(0.f,0.f,0.f,0.f);
            float s = 0.f, ss = 0.f;
            {
                float4 p = ((const float4*)(hp + (size_t)row * CR))[lane];
                float4 q = ((const float4*)(h1 + (size_t)row * CR))[lane];
                float4 b = ((const float4*)b_proj)[lane];
                c0 = make_float4(p.x + q.x + b.x, p.y + q.y + b.y,
                                 p.z + q.z + b.z, p.w + q.w + b.w);
                s  += c0.x + c0.y + c0.z + c0.w;
                ss += c0.x * c0.x + c0.y * c0.y + c0.z * c0.z + c0.w * c0.w;
            }
            if (lane < 32) {
                float4 p = ((const float4*)(hp + (size_t)row * CR))[64 + lane];
                float4 q = ((const float4*)(h1 + (size_t)row * CR))[64 + lane];
                float4 b = ((const float4*)b_proj)[64 + lane];
                c1 = make_float4(p.x + q.x + b.x, p.y + q.y + b.y,
                                 p.z + q.z + b.z, p.w + q.w + b.w);
                s  += c1.x + c1.y + c1.z + c1.w;
                ss += c1.x * c1.x + c1.y * c1.y + c1.z * c1.z + c1.w * c1.w;
            }
#pragma unroll
            for (int off = 1; off < 64; off <<= 1) {
                s += __shfl_xor(s, off, 64); ss += __shfl_xor(ss, off, 64);
            }
            const float mu = s / CR, rs = rsqrtf(ss / CR - mu * mu + EPS);
            {
                ((float4*)(hbuf + (size_t)row * CR))[lane] = c0;
                float4 gv = ((const float4*)ln1_g)[lane];
                float4 bv = ((const float4*)ln1_b)[lane];
                uint2 pk;
                pk.x = packbf2((c0.x - mu) * rs * gv.x + bv.x, (c0.y - mu) * rs * gv.y + bv.y);
                pk.y = packbf2((c0.z - mu) * rs * gv.z + bv.z, (c0.w - mu) * rs * gv.w + bv.w);
                *(uint2*)(yb + (size_t)row * CR + lane * 4) = pk;
            }
            if (lane < 32) {
                ((float4*)(hbuf + (size_t)row * CR))[64 + lane] = c1;
                float4 gv = ((const float4*)ln1_g)[64 + lane];
                float4 bv = ((const float4*)ln1_b)[64 + lane];
                uint2 pk;
                pk.x = packbf2((c1.x - mu) * rs * gv.x + bv.x, (c1.y - mu) * rs * gv.y + bv.y);
                pk.y = packbf2((c1.z - mu) * rs * gv.z + bv.z, (c1.w - mu) * rs * gv.w + bv.w);
                *(uint2*)(yb + (size_t)row * CR + (64 + lane) * 4) = pk;
            }
        }
    }
    __threadfence(); grid.sync();

    // ---- P3: qkv gemm: qk (q scaled) + V^T = y @ wqkv^T, 576 jobs ----
#pragma unroll 1
    for (int job = bid; job < 576; job += nblk) {
        const int n0 = (job % 9) * 128;
        const int m0 = (job / 9) * 128;
        gemm_tile<CR, 12, 1>(yb, wqkv, m0, n0, 0, sm.g.A, sm.g.B, qkb, vtb);
    }
    __threadfence(); grid.sync();

    // ---- P4: attention + residual, 768 jobs ----
#pragma unroll 1
    for (int job = bid; job < 768; job += nblk)
        attn_tile(job & 7, job >> 3, qkb, vtb, hbuf, out, sm.at.Ks, sm.at.Vs, sm.at.Ps);
}

// ================= fallback multi-kernel path (R7-proven, 165 us) =================

__global__ __launch_bounds__(256) void ln0_cast_k(
    const float* __restrict__ x,
    const float* __restrict__ g, const float* __restrict__ bt,
    unsigned short* __restrict__ a0,
    const float* __restrict__ wpf, const float* __restrict__ wq,
    const float* __restrict__ wk, const float* __restrict__ wv,
    unsigned short* __restrict__ wpo, unsigned short* __restrict__ wqkvo)
{
    const int bx = blockIdx.x;
    const int t = threadIdx.x;
    if (bx >= MROWS) {
        int i = (bx - MROWS) * 256 + t;
        const float* src; unsigned short* dst; int off;
        if (i < 73728) { src = wpf; dst = wpo; off = i; }
        else {
            int j = i - 73728;
            int sel = j / 36864; off = j % 36864;
            src = sel == 0 ? wq : (sel == 1 ? wk : wv);
            dst = wqkvo + (size_t)sel * 147456;
        }
        float4 v = ((const float4*)src)[off];
        ((ushort4*)dst)[off] = make_ushort4(f2bf(v.x), f2bf(v.y), f2bf(v.z), f2bf(v.w));
        return;
    }
    const int nv = DIM >> 2;
    const float* a = x + (size_t)bx * DIM;
    float4 val = make_float4(0.f, 0.f, 0.f, 0.f);
    float s = 0.f, ss = 0.f;
    if (t < nv) {
        val = ((const float4*)a)[t];
        s = val.x + val.y + val.z + val.w;
        ss = val.x * val.x + val.y * val.y + val.z * val.z + val.w * val.w;
    }
    for (int off = 32; off; off >>= 1) {
        s  += __shfl_down(s, off, 64);
        ss += __shfl_down(ss, off, 64);
    }
    __shared__ float rS[4], rSS[4];
    __shared__ float sh_mu, sh_rs;
    int lane = t & 63, w = t >> 6;
    if (lane == 0) { rS[w] = s; rSS[w] = ss; }
    __syncthreads();
    if (t == 0) {
        float S = rS[0] + rS[1] + rS[2] + rS[3];
        float SS = rSS[0] + rSS[1] + rSS[2] + rSS[3];
        float m = S / DIM;
        sh_mu = m;
        sh_rs = rsqrtf(SS / DIM - m * m + EPS);
    }
    __syncthreads();
    if (t < nv) {
        float m = sh_mu, r = sh_rs;
        float4 gv = ((const float4*)g)[t];
        float4 bv = ((const float4*)bt)[t];
        ((ushort4*)(a0 + (size_t)bx * DIM))[t] = make_ushort4(
            f2bf((val.x - m) * r * gv.x + bv.x),
            f2bf((val.y - m) * r * gv.y + bv.y),
            f2bf((val.z - m) * r * gv.z + bv.z),
            f2bf((val.w - m) * r * gv.w + bv.w));
    }
}

__global__ __launch_bounds__(128) void ln1_sum_k(
    const float* __restrict__ h0, const float* __restrict__ h1,
    const float* __restrict__ bias,
    const float* __restrict__ g, const float* __restrict__ bt,
    float* __restrict__ hs, unsigned short* __restrict__ y)
{
    const int row = blockIdx.x;
    const int t = threadIdx.x;
    const int nv = CR >> 2;
    float4 val = make_float4(0.f, 0.f, 0.f, 0.f);
    float s = 0.f, ss = 0.f;
    if (t < nv) {
        float4 v0 = ((const float4*)(h0 + (size_t)row * CR))[t];
        float4 v1 = ((const float4*)(h1 + (size_t)row * CR))[t];
        float4 bv = ((const float4*)bias)[t];
        val = make_float4(v0.x + v1.x + bv.x, v0.y + v1.y + bv.y,
                          v0.z + v1.z + bv.z, v0.w + v1.w + bv.w);
        ((float4*)(hs + (size_t)row * CR))[t] = val;
        s = val.x + val.y + val.z + val.w;
        ss = val.x * val.x + val.y * val.y + val.z * val.z + val.w * val.w;
    }
    for (int off = 32; off; off >>= 1) {
        s  += __shfl_down(s, off, 64);
        ss += __shfl_down(ss, off, 64);
    }
    __shared__ float rS[2], rSS[2];
    __shared__ float sh_mu, sh_rs;
    int lane = t & 63, w = t >> 6;
    if (lane == 0) { rS[w] = s; rSS[w] = ss; }
    __syncthreads();
    if (t == 0) {
        float S = rS[0] + rS[1];
        float SS = rSS[0] + rSS[1];
        float m = S / CR;
        sh_mu = m;
        sh_rs = rsqrtf(SS / CR - m * m + EPS);
    }
    __syncthreads();
    if (t < nv) {
        float m = sh_mu, r = sh_rs;
        float4 gv = ((const float4*)g)[t];
        float4 bv = ((const float4*)bt)[t];
        ((ushort4*)(y + (size_t)row * CR))[t] = make_ushort4(
            f2bf((val.x - m) * r * gv.x + bv.x),
            f2bf((val.y - m) * r * gv.y + bv.y),
            f2bf((val.z - m) * r * gv.z + bv.z),
            f2bf((val.w - m) * r * gv.w + bv.w));
    }
}

template<int KD, int NITER, int MODE>
__global__ __launch_bounds__(256) void gemm_mfma_k(
    const unsigned short* __restrict__ A,
    const unsigned short* __restrict__ W,
    void* __restrict__ C0, void* __restrict__ C1)
{
    __shared__ unsigned short Asm[2 * 128 * 32];
    __shared__ unsigned short Bsm[2 * 128 * 32];
    const int m0 = blockIdx.y * 128;
    const int n0 = blockIdx.x * 128;
    const int koff = blockIdx.z * (NITER * 32);
    void* C0z = (MODE == 0) ? (void*)((float*)C0 + (size_t)blockIdx.z * MROWS * CR) : C0;
    gemm_tile<KD, NITER, MODE>(A, W, m0, n0, koff, Asm, Bsm, C0z, C1);
}

__global__ __launch_bounds__(256) void attn_mfma_k(
    const unsigned short* __restrict__ qk, const unsigned short* __restrict__ vt,
    const float* __restrict__ h, float* __restrict__ out)
{
    __shared__ unsigned short Ks[64 * 40];
    __shared__ unsigned short Vs[32 * 72];
    __shared__ unsigned short Ps[4 * 32 * 72];
    attn_tile(blockIdx.x, blockIdx.y, qk, vt, h, out, Ks, Vs, Ps);
}

extern "C" void kernel_launch(void* const* d_in, const int* in_sizes, int n_in,
                              void* d_out, int out_size, void* d_ws, size_t ws_size,
                              hipStream_t stream) {
    const float* x      = (const float*)d_in[0];
    const float* ln0_g  = (const float*)d_in[1];
    const float* ln0_b  = (const float*)d_in[2];
    const float* w_proj = (const float*)d_in[3];
    const float* b_proj = (const float*)d_in[4];
    const float* ln1_g  = (const float*)d_in[5];
    const float* ln1_b  = (const float*)d_in[6];
    const float* wq     = (const float*)d_in[7];
    const float* wk     = (const float*)d_in[8];
    const float* wv     = (const float*)d_in[9];
    float* out = (float*)d_out;

    // ws layout (64.4 MB): qkb aliases a0 (a0 dead after P1)
    char* base = (char*)d_ws;
    unsigned short* a0   = (unsigned short*)base;               // 8192*768*2 = 12,582,912
    unsigned short* qkb  = (unsigned short*)base;               // alias
    float*          hp   = (float*)(base + 12582912);           // 2 x 8192*384*4
    float*          hbuf = (float*)(base + 37748736);           // 8192*384*4
    unsigned short* yb   = (unsigned short*)(base + 50331648);  // 8192*384*2
    unsigned short* vtb  = (unsigned short*)(base + 56623104);  // 384*8192*2
    unsigned short* wp   = (unsigned short*)(base + 62914560);  // 384*768*2
    unsigned short* wqkv = (unsigned short*)(base + 63504384);  // 1152*384*2

    // size grid from measured occupancy (pure host query; deterministic, capture-safe)
    int maxb = 0;
    hipError_t occ = hipOccupancyMaxActiveBlocksPerMultiprocessor(&maxb, fused_all, 256, 0);
    int nblk = 256;
    if (occ == hipSuccess && maxb >= 1) {
        nblk = maxb * 256;
        if (nblk > 512) nblk = 512;
    }

    void* args[] = { (void*)&x, (void*)&ln0_g, (void*)&ln0_b, (void*)&w_proj, (void*)&b_proj,
                     (void*)&ln1_g, (void*)&ln1_b, (void*)&wq, (void*)&wk, (void*)&wv,
                     (void*)&a0, (void*)&wp, (void*)&wqkv, (void*)&hp, (void*)&hbuf,
                     (void*)&yb, (void*)&qkb, (void*)&vtb, (void*)&out, (void*)&nblk };
    hipError_t e = hipLaunchCooperativeKernel((void*)fused_all, dim3(nblk), dim3(256),
                                              args, 0, stream);
    if (e != hipSuccess) {
        // fallback: proven R7 five-kernel pipeline
        ln0_cast_k<<<MROWS + 720, 256, 0, stream>>>(x, ln0_g, ln0_b, a0,
                                                    w_proj, wq, wk, wv, wp, wqkv);
        gemm_mfma_k<DIM, 12, 0><<<dim3(CR / 128, MROWS / 128, 2), 256, 0, stream>>>(
            a0, wp, hp, nullptr);
        ln1_sum_k<<<MROWS, 128, 0, stream>>>(hp, hp + (size_t)MROWS * CR, b_proj,
                                             ln1_g, ln1_b, hbuf, yb);
        gemm_mfma_k<CR, 12, 1><<<dim3(1152 / 128, MROWS / 128, 1), 256, 0, stream>>>(
            yb, wqkv, qkb, vtb);
        attn_mfma_k<<<dim3(NN / 128, BB * HEADS), 256, 0, stream>>>(qkb, vtb, hbuf, out);
    }
}

// Round 10
// 161.548 us; speedup vs baseline: 2.7621x; 2.7621x over previous
//
#include <hip/hip_runtime.h>
#include <hip/hip_bf16.h>
#include <math.h>

#define BB 8
#define NN 1024
#define DIM 768
#define HEADS 12
#define CR 384
#define HD 32
#define MROWS (BB*NN)   // 8192
#define EPS 1e-5f
#define SCALE_Q 0.25503486f   // (1/sqrt(32)) * log2(e): P = exp2(s) directly

typedef __attribute__((ext_vector_type(8))) __bf16 bf16x8;
typedef __attribute__((ext_vector_type(8))) unsigned short u16x8;
typedef __attribute__((ext_vector_type(4))) float f32x4;

__device__ __forceinline__ unsigned short f2bf(float f) {
    unsigned int u = __float_as_uint(f);
    u += 0x7fffu + ((u >> 16) & 1u);   // RNE; finite inputs only
    return (unsigned short)(u >> 16);
}

__device__ __forceinline__ unsigned int packbf2(float lo, float hi) {
    __hip_bfloat162 h2 = __float22bfloat162_rn(make_float2(lo, hi));
    unsigned int u; __builtin_memcpy(&u, &h2, sizeof(u));
    return u;
}

// async global->LDS, 16B/lane; LDS dest = wave-uniform base + lane*16
__device__ __forceinline__ void async_cp16(const unsigned short* g, unsigned short* l) {
    __builtin_amdgcn_global_load_lds(
        (const __attribute__((address_space(1))) unsigned int*)g,
        (__attribute__((address_space(3))) unsigned int*)l, 16, 0, 0);
}

// ---------------- fused LN0 -> bf16  +  weight casts (partitioned grid) ----------------
__global__ __launch_bounds__(256) void ln0_cast(
    const float* __restrict__ x,
    const float* __restrict__ g, const float* __restrict__ bt,
    unsigned short* __restrict__ a0,
    const float* __restrict__ wpf, const float* __restrict__ wq,
    const float* __restrict__ wk, const float* __restrict__ wv,
    unsigned short* __restrict__ wpo, unsigned short* __restrict__ wqkvo)
{
    const int bx = blockIdx.x;
    const int t = threadIdx.x;
    if (bx >= MROWS) {   // weight-cast partition
        int i = (bx - MROWS) * 256 + t;       // float4 index, covers 184320
        const float* src; unsigned short* dst; int off;
        if (i < 73728) { src = wpf; dst = wpo; off = i; }
        else {
            int j = i - 73728;
            int sel = j / 36864; off = j % 36864;
            src = sel == 0 ? wq : (sel == 1 ? wk : wv);
            dst = wqkvo + (size_t)sel * 147456;
        }
        float4 v = ((const float4*)src)[off];
        ((ushort4*)dst)[off] = make_ushort4(f2bf(v.x), f2bf(v.y), f2bf(v.z), f2bf(v.w));
        return;
    }
    const int nv = DIM >> 2;                  // 192 float4
    const float* a = x + (size_t)bx * DIM;
    float4 val = make_float4(0.f, 0.f, 0.f, 0.f);
    float s = 0.f, ss = 0.f;
    if (t < nv) {
        val = ((const float4*)a)[t];
        s = val.x + val.y + val.z + val.w;
        ss = val.x * val.x + val.y * val.y + val.z * val.z + val.w * val.w;
    }
    for (int off = 32; off; off >>= 1) {
        s  += __shfl_down(s, off, 64);
        ss += __shfl_down(ss, off, 64);
    }
    __shared__ float rS[4], rSS[4];
    __shared__ float sh_mu, sh_rs;
    int lane = t & 63, w = t >> 6;
    if (lane == 0) { rS[w] = s; rSS[w] = ss; }
    __syncthreads();
    if (t == 0) {
        float S = rS[0] + rS[1] + rS[2] + rS[3];
        float SS = rSS[0] + rSS[1] + rSS[2] + rSS[3];
        float m = S / DIM;
        sh_mu = m;
        sh_rs = rsqrtf(SS / DIM - m * m + EPS);
    }
    __syncthreads();
    if (t < nv) {
        float m = sh_mu, r = sh_rs;
        float4 gv = ((const float4*)g)[t];
        float4 bv = ((const float4*)bt)[t];
        ((ushort4*)(a0 + (size_t)bx * DIM))[t] = make_ushort4(
            f2bf((val.x - m) * r * gv.x + bv.x),
            f2bf((val.y - m) * r * gv.y + bv.y),
            f2bf((val.z - m) * r * gv.z + bv.z),
            f2bf((val.w - m) * r * gv.w + bv.w));
    }
}

// ---------------- ln1_sum: hs = h0+h1+bias; y = bf16(LN1(hs)) ----------------
__global__ __launch_bounds__(128) void ln1_sum(
    const float* __restrict__ h0, const float* __restrict__ h1,
    const float* __restrict__ bias,
    const float* __restrict__ g, const float* __restrict__ bt,
    float* __restrict__ hs, unsigned short* __restrict__ y)
{
    const int row = blockIdx.x;
    const int t = threadIdx.x;
    const int nv = CR >> 2;                   // 96 float4
    float4 val = make_float4(0.f, 0.f, 0.f, 0.f);
    float s = 0.f, ss = 0.f;
    if (t < nv) {
        float4 v0 = ((const float4*)(h0 + (size_t)row * CR))[t];
        float4 v1 = ((const float4*)(h1 + (size_t)row * CR))[t];
        float4 bv = ((const float4*)bias)[t];
        val = make_float4(v0.x + v1.x + bv.x, v0.y + v1.y + bv.y,
                          v0.z + v1.z + bv.z, v0.w + v1.w + bv.w);
        ((float4*)(hs + (size_t)row * CR))[t] = val;
        s = val.x + val.y + val.z + val.w;
        ss = val.x * val.x + val.y * val.y + val.z * val.z + val.w * val.w;
    }
    for (int off = 32; off; off >>= 1) {
        s  += __shfl_down(s, off, 64);
        ss += __shfl_down(ss, off, 64);
    }
    __shared__ float rS[2], rSS[2];
    __shared__ float sh_mu, sh_rs;
    int lane = t & 63, w = t >> 6;
    if (lane == 0) { rS[w] = s; rSS[w] = ss; }
    __syncthreads();
    if (t == 0) {
        float S = rS[0] + rS[1];
        float SS = rSS[0] + rSS[1];
        float m = S / CR;
        sh_mu = m;
        sh_rs = rsqrtf(SS / CR - m * m + EPS);
    }
    __syncthreads();
    if (t < nv) {
        float m = sh_mu, r = sh_rs;
        float4 gv = ((const float4*)g)[t];
        float4 bv = ((const float4*)bt)[t];
        ((ushort4*)(y + (size_t)row * CR))[t] = make_ushort4(
            f2bf((val.x - m) * r * gv.x + bv.x),
            f2bf((val.y - m) * r * gv.y + bv.y),
            f2bf((val.z - m) * r * gv.z + bv.z),
            f2bf((val.w - m) * r * gv.w + bv.w));
    }
}

// ---------------- bf16 MFMA GEMM, 128x128 tile, dbuf LDS + prefetch, split-K (R7-proven) ----------------
// MODE 0: f32 partial out (pitch CR) -> C0 + blockIdx.z*MROWS*CR
// MODE 1: qkv epilogue: cols<384 -> bf16 q*SCALE_Q into C0 pitch 768; 384..767 -> bf16 k;
//         cols>=768 -> V^T bf16 into C1 [ch][token] pitch 8192.
template<int KD, int NITER, int MODE>
__global__ __launch_bounds__(256) void gemm_mfma(
    const unsigned short* __restrict__ A,
    const unsigned short* __restrict__ W,
    void* __restrict__ C0, void* __restrict__ C1)
{
    __shared__ unsigned short Asm[2 * 128 * 32];   // 16 KB
    __shared__ unsigned short Bsm[2 * 128 * 32];
    const int t = threadIdx.x;
    const int wave = t >> 6, lane = t & 63;
    const int l15 = lane & 15, quad = lane >> 4;
    const int m0 = blockIdx.y * 128;
    const int n0 = blockIdx.x * 128;
    const int koff = blockIdx.z * (NITER * 32);
    const int wm = (wave & 1) * 64, wn = (wave >> 1) * 64;

    const int srow = lane >> 2;
    const int skq  = (lane & 3) * 8;
    const unsigned short* gA = A + (size_t)(m0 + wave * 32 + srow) * KD + koff + skq;
    const unsigned short* gB = W + (size_t)(n0 + wave * 32 + srow) * KD + koff + skq;
    unsigned short* lA = Asm + wave * 1024;
    unsigned short* lB = Bsm + wave * 1024;

    async_cp16(gA, lA);
    async_cp16(gA + (size_t)16 * KD, lA + 512);
    async_cp16(gB, lB);
    async_cp16(gB + (size_t)16 * KD, lB + 512);

    f32x4 acc[4][4];
#pragma unroll
    for (int i = 0; i < 4; i++)
#pragma unroll
        for (int j = 0; j < 4; j++) acc[i][j] = (f32x4){0.f, 0.f, 0.f, 0.f};

    for (int it = 0; it < NITER; it++) {
        __syncthreads();                     // buf[it&1] staged (vmcnt drained at barrier)
        const int cur = it & 1;
        if (it + 1 < NITER) {
            const int noff = (cur ^ 1) * 4096;
            async_cp16(gA + (it + 1) * 32, lA + noff);
            async_cp16(gA + (size_t)16 * KD + (it + 1) * 32, lA + noff + 512);
            async_cp16(gB + (it + 1) * 32, lB + noff);
            async_cp16(gB + (size_t)16 * KD + (it + 1) * 32, lB + noff + 512);
        }
        const unsigned short* Ab = Asm + cur * 4096;
        const unsigned short* Bb = Bsm + cur * 4096;
        bf16x8 af[4], bfr[4];
#pragma unroll
        for (int i = 0; i < 4; i++)
            af[i] = *(const bf16x8*)(Ab + (wm + i * 16 + l15) * 32 + quad * 8);
#pragma unroll
        for (int j = 0; j < 4; j++)
            bfr[j] = *(const bf16x8*)(Bb + (wn + j * 16 + l15) * 32 + quad * 8);
#pragma unroll
        for (int i = 0; i < 4; i++)
#pragma unroll
            for (int j = 0; j < 4; j++)
                acc[i][j] = __builtin_amdgcn_mfma_f32_16x16x32_bf16(af[i], bfr[j], acc[i][j], 0, 0, 0);
    }

    if constexpr (MODE == 0) {
        float* C = (float*)C0 + (size_t)blockIdx.z * MROWS * CR;
#pragma unroll
        for (int i = 0; i < 4; i++)
#pragma unroll
            for (int j = 0; j < 4; j++)
#pragma unroll
                for (int reg = 0; reg < 4; reg++) {
                    int row = m0 + wm + i * 16 + quad * 4 + reg;
                    int col = n0 + wn + j * 16 + l15;
                    C[(size_t)row * CR + col] = acc[i][j][reg];
                }
    } else {
        unsigned short* Cqk = (unsigned short*)C0;    // [token][768] bf16: q(scaled)|k
        unsigned short* Vt  = (unsigned short*)C1;    // [ch][8192] bf16
#pragma unroll
        for (int i = 0; i < 4; i++)
#pragma unroll
            for (int j = 0; j < 4; j++) {
                const int colbase = n0 + wn + j * 16;
                const int token0 = m0 + wm + i * 16 + quad * 4;
                if (colbase < DIM) {
                    const float sc = (colbase < CR) ? SCALE_Q : 1.f;
#pragma unroll
                    for (int reg = 0; reg < 4; reg++)
                        Cqk[(size_t)(token0 + reg) * DIM + colbase + l15] = f2bf(acc[i][j][reg] * sc);
                } else {
                    const int ch = colbase - DIM + l15;
                    uint2 pk;
                    pk.x = packbf2(acc[i][j][0], acc[i][j][1]);
                    pk.y = packbf2(acc[i][j][2], acc[i][j][3]);
                    *(uint2*)(Vt + (size_t)ch * MROWS + token0) = pk;
                }
            }
    }
}

// ---------------- MFMA flash attention: 128-q blocks, S^T core, DBUF K/V staging ----------------
// One barrier per kt: read buf[kt&1] while writing buf[kt&1^1] (last read 2 barriers ago).
__global__ __launch_bounds__(256) void attn_mfma(
    const unsigned short* __restrict__ qk,   // [8192][768] bf16: q*SCALE_Q | k
    const unsigned short* __restrict__ vt,   // [384][8192] bf16: V^T
    const float* __restrict__ h, float* __restrict__ out)
{
    const int qt = blockIdx.x;                // 0..7 (128-q tiles)
    const int bh = blockIdx.y;                // 0..95
    const int b = bh / HEADS, head = bh % HEADS;
    const int hc = head * HD;
    const int t = threadIdx.x;
    const int wave = t >> 6, lane = t & 63;
    const int l15 = lane & 15, quad = lane >> 4;
    const int q0 = qt * 128;

    __shared__ unsigned short Ks[2][64 * 40];  // [key][dim] pitch 40, double-buffered
    __shared__ unsigned short Vs[2][32 * 72];  // [ch][key] pitch 72, double-buffered
    __shared__ unsigned short Ps[4][32 * 72];  // wave-private P [q(32)][key] pitch 72
    unsigned short* Pw = Ps[wave];

    bf16x8 qa[2];
#pragma unroll
    for (int qi = 0; qi < 2; qi++)
        qa[qi] = *(const bf16x8*)(qk + (size_t)(b * NN + q0 + wave * 32 + qi * 16 + l15) * DIM
                                  + hc + quad * 8);

    // staging maps (coalesced): K: 4 lanes per key row; V: 8 lanes per ch row
    const int rr = t >> 2, seg = t & 3;
    const unsigned short* gK = qk + (size_t)(b * NN + rr) * DIM + CR + hc + seg * 8;
    const int vch = wave * 8 + (lane >> 3), vko = (lane & 7) * 8;
    const unsigned short* gV = vt + (size_t)(hc + vch) * MROWS + b * NN + vko;

    // stage kt=0, prefetch kt=1
    {
        u16x8 k0 = *(const u16x8*)gK;
        u16x8 v0 = *(const u16x8*)gV;
        *(u16x8*)(Ks[0] + rr * 40 + seg * 8) = k0;
        *(u16x8*)(Vs[0] + vch * 72 + vko) = v0;
    }
    u16x8 kreg = *(const u16x8*)(gK + (size_t)64 * DIM);
    u16x8 vreg = *(const u16x8*)(gV + 64);

    f32x4 o[2][2] = {{{0.f,0.f,0.f,0.f},{0.f,0.f,0.f,0.f}},
                     {{0.f,0.f,0.f,0.f},{0.f,0.f,0.f,0.f}}};
    float lpart[2] = {0.f, 0.f};
    __syncthreads();                           // tile 0 visible

    for (int kt = 0; kt < 16; kt++) {
        const int cur = kt & 1;
        const unsigned short* Kc = Ks[cur];
        const unsigned short* Vc = Vs[cur];

        // K A-frags shared across both q-subtiles
        bf16x8 kb[4];
#pragma unroll
        for (int nt = 0; nt < 4; nt++)
            kb[nt] = *(const bf16x8*)(Kc + (nt * 16 + l15) * 40 + quad * 8);

#pragma unroll
        for (int qi = 0; qi < 2; qi++) {
            f32x4 s[4];
#pragma unroll
            for (int nt = 0; nt < 4; nt++) {
                f32x4 z = {0.f, 0.f, 0.f, 0.f};
                s[nt] = __builtin_amdgcn_mfma_f32_16x16x32_bf16(kb[nt], qa[qi], z, 0, 0, 0);
            }
#pragma unroll
            for (int nt = 0; nt < 4; nt++) {
                float e0 = __builtin_amdgcn_exp2f(s[nt][0]);
                float e1 = __builtin_amdgcn_exp2f(s[nt][1]);
                float e2 = __builtin_amdgcn_exp2f(s[nt][2]);
                float e3 = __builtin_amdgcn_exp2f(s[nt][3]);
                lpart[qi] += (e0 + e1) + (e2 + e3);
                uint2 pk;
                pk.x = packbf2(e0, e1);
                pk.y = packbf2(e2, e3);
                *(uint2*)(Pw + (qi * 16 + l15) * 72 + nt * 16 + quad * 4) = pk;
            }
        }

        bf16x8 vb[2][2];
#pragma unroll
        for (int kk = 0; kk < 2; kk++)
#pragma unroll
            for (int nt2 = 0; nt2 < 2; nt2++)
                vb[kk][nt2] = *(const bf16x8*)(Vc + (nt2 * 16 + l15) * 72 + kk * 32 + quad * 8);

#pragma unroll
        for (int qi = 0; qi < 2; qi++)
#pragma unroll
            for (int kk = 0; kk < 2; kk++) {
                bf16x8 pa = *(const bf16x8*)(Pw + (qi * 16 + l15) * 72 + kk * 32 + quad * 8);
#pragma unroll
                for (int nt2 = 0; nt2 < 2; nt2++)
                    o[qi][nt2] = __builtin_amdgcn_mfma_f32_16x16x32_bf16(pa, vb[kk][nt2], o[qi][nt2], 0, 0, 0);
            }

        // write next tile into the other buffer (its readers passed the kt-1 barrier)
        if (kt < 15) {
            *(u16x8*)(Ks[cur ^ 1] + rr * 40 + seg * 8) = kreg;
            *(u16x8*)(Vs[cur ^ 1] + vch * 72 + vko) = vreg;
            if (kt < 14) {
                kreg = *(const u16x8*)(gK + (size_t)(kt + 2) * 64 * DIM);
                vreg = *(const u16x8*)(gV + (kt + 2) * 64);
            }
        }
        __syncthreads();                       // single barrier per kt
    }

    // epilogue per q-subtile
#pragma unroll
    for (int qi = 0; qi < 2; qi++) {
        float l = lpart[qi];
        l += __shfl_xor(l, 16, 64);
        l += __shfl_xor(l, 32, 64);
        const float linv = 1.f / l;
#pragma unroll
        for (int reg = 0; reg < 4; reg++) {
            const float li = __shfl(linv, quad * 4 + reg, 64);
            const size_t row = (size_t)(b * NN + q0 + wave * 32 + qi * 16 + quad * 4 + reg);
#pragma unroll
            for (int nt2 = 0; nt2 < 2; nt2++) {
                size_t idx = row * CR + hc + nt2 * 16 + l15;
                out[idx] = h[idx] + o[qi][nt2][reg] * li;
            }
        }
    }
}

extern "C" void kernel_launch(void* const* d_in, const int* in_sizes, int n_in,
                              void* d_out, int out_size, void* d_ws, size_t ws_size,
                              hipStream_t stream) {
    const float* x      = (const float*)d_in[0];
    const float* ln0_g  = (const float*)d_in[1];
    const float* ln0_b  = (const float*)d_in[2];
    const float* w_proj = (const float*)d_in[3];
    const float* b_proj = (const float*)d_in[4];
    const float* ln1_g  = (const float*)d_in[5];
    const float* ln1_b  = (const float*)d_in[6];
    const float* wq     = (const float*)d_in[7];
    const float* wk     = (const float*)d_in[8];
    const float* wv     = (const float*)d_in[9];
    float* out = (float*)d_out;

    // ws layout (64.4 MB): qkb aliases a0 (a0 dead after gemm1 reads it)
    char* base = (char*)d_ws;
    unsigned short* a0   = (unsigned short*)base;               // 8192*768*2 = 12,582,912
    unsigned short* qkb  = (unsigned short*)base;               // alias
    float*          hp   = (float*)(base + 12582912);           // 2 x 8192*384*4
    float*          hbuf = (float*)(base + 37748736);           // 8192*384*4
    unsigned short* yb   = (unsigned short*)(base + 50331648);  // 8192*384*2
    unsigned short* vtb  = (unsigned short*)(base + 56623104);  // 384*8192*2
    unsigned short* wp   = (unsigned short*)(base + 62914560);  // 384*768*2
    unsigned short* wqkv = (unsigned short*)(base + 63504384);  // 1152*384*2

    // 1. a0 = bf16(LN0(x)) + weight casts (fused, partitioned grid)
    ln0_cast<<<MROWS + 720, 256, 0, stream>>>(x, ln0_g, ln0_b, a0,
                                              w_proj, wq, wk, wv, wp, wqkv);
    // 2. split-K gemm1: hp[z] = a0 @ wp^T (K-half z)
    gemm_mfma<DIM, 12, 0><<<dim3(CR / 128, MROWS / 128, 2), 256, 0, stream>>>(
        a0, wp, hp, nullptr);
    // 3. hsum = hp0+hp1+b_proj; y = bf16(LN1(hsum))
    ln1_sum<<<MROWS, 128, 0, stream>>>(hp, hp + (size_t)MROWS * CR, b_proj,
                                       ln1_g, ln1_b, hbuf, yb);
    // 4. qk (q scaled) + V^T = y @ wqkv^T
    gemm_mfma<CR, 12, 1><<<dim3(1152 / 128, MROWS / 128, 1), 256, 0, stream>>>(
        yb, wqkv, qkb, vtb);
    // 5. out = hsum + attention
    attn_mfma<<<dim3(NN / 128, BB * HEADS), 256, 0, stream>>>(qkb, vtb, hbuf, out);
}

// Round 11
// 158.742 us; speedup vs baseline: 2.8109x; 1.0177x over previous
//
#include <hip/hip_runtime.h>
#include <hip/hip_bf16.h>
#include <math.h>

#define BB 8
#define NN 1024
#define DIM 768
#define HEADS 12
#define CR 384
#define HD 32
#define MROWS (BB*NN)   // 8192
#define EPS 1e-5f
#define SCALE_Q 0.25503486f   // (1/sqrt(32)) * log2(e): P = exp2(s) directly

typedef __attribute__((ext_vector_type(8))) __bf16 bf16x8;
typedef __attribute__((ext_vector_type(8))) unsigned short u16x8;
typedef __attribute__((ext_vector_type(4))) float f32x4;

__device__ __forceinline__ unsigned short f2bf(float f) {
    unsigned int u = __float_as_uint(f);
    u += 0x7fffu + ((u >> 16) & 1u);   // RNE; finite inputs only
    return (unsigned short)(u >> 16);
}

__device__ __forceinline__ unsigned int packbf2(float lo, float hi) {
    __hip_bfloat162 h2 = __float22bfloat162_rn(make_float2(lo, hi));
    unsigned int u; __builtin_memcpy(&u, &h2, sizeof(u));
    return u;
}

__device__ __forceinline__ float bf2f(unsigned short u) {
    unsigned int w = ((unsigned int)u) << 16;
    return __uint_as_float(w);
}

// async global->LDS, 16B/lane; LDS dest = wave-uniform base + lane*16
__device__ __forceinline__ void async_cp16(const unsigned short* g, unsigned short* l) {
    __builtin_amdgcn_global_load_lds(
        (const __attribute__((address_space(1))) unsigned int*)g,
        (__attribute__((address_space(3))) unsigned int*)l, 16, 0, 0);
}

// ---------------- LN0 (wave-per-row, all lanes active) + weight casts (partitioned) ----------------
// blocks [0,2048): 4 rows each (one per wave).  blocks [2048, 2048+720): weight-cast chunks.
__global__ __launch_bounds__(256) void ln0_cast(
    const float* __restrict__ x,
    const float* __restrict__ g, const float* __restrict__ bt,
    unsigned short* __restrict__ a0,
    const float* __restrict__ wpf, const float* __restrict__ wq,
    const float* __restrict__ wk, const float* __restrict__ wv,
    unsigned short* __restrict__ wpo, unsigned short* __restrict__ wqkvo)
{
    const int bx = blockIdx.x;
    const int t = threadIdx.x;
    if (bx >= 2048) {   // weight-cast partition
        int i = (bx - 2048) * 256 + t;        // float4 index, covers 184320
        const float* src; unsigned short* dst; int off;
        if (i < 73728) { src = wpf; dst = wpo; off = i; }
        else {
            int j = i - 73728;
            int sel = j / 36864; off = j % 36864;
            src = sel == 0 ? wq : (sel == 1 ? wk : wv);
            dst = wqkvo + (size_t)sel * 147456;
        }
        float4 v = ((const float4*)src)[off];
        uint2 pk; pk.x = packbf2(v.x, v.y); pk.y = packbf2(v.z, v.w);
        ((uint2*)dst)[off] = pk;
        return;
    }
    // LN partition: wave-per-row, 4 rows per block
    const int wave = t >> 6, lane = t & 63;
    const int row = bx * 4 + wave;
    const float* a = x + (size_t)row * DIM;
    float4 v[3]; float s = 0.f, ss = 0.f;
#pragma unroll
    for (int c = 0; c < 3; c++) {
        v[c] = ((const float4*)a)[lane + c * 64];
        s  += v[c].x + v[c].y + v[c].z + v[c].w;
        ss += v[c].x * v[c].x + v[c].y * v[c].y + v[c].z * v[c].z + v[c].w * v[c].w;
    }
#pragma unroll
    for (int off = 1; off < 64; off <<= 1) {
        s += __shfl_xor(s, off, 64); ss += __shfl_xor(ss, off, 64);
    }
    const float mu = s / DIM, rs = rsqrtf(ss / DIM - mu * mu + EPS);
#pragma unroll
    for (int c = 0; c < 3; c++) {
        float4 gv = ((const float4*)g)[lane + c * 64];
        float4 bv = ((const float4*)bt)[lane + c * 64];
        uint2 pk;
        pk.x = packbf2((v[c].x - mu) * rs * gv.x + bv.x, (v[c].y - mu) * rs * gv.y + bv.y);
        pk.y = packbf2((v[c].z - mu) * rs * gv.z + bv.z, (v[c].w - mu) * rs * gv.w + bv.w);
        *(uint2*)(a0 + (size_t)row * DIM + (lane + c * 64) * 4) = pk;
    }
}

// ---------------- ln1_sum: hs = bf16(h0)+bf16(h1)+bias; y = bf16(LN1(hs)) ----------------
__global__ __launch_bounds__(128) void ln1_sum(
    const unsigned short* __restrict__ h0, const unsigned short* __restrict__ h1,
    const float* __restrict__ bias,
    const float* __restrict__ g, const float* __restrict__ bt,
    float* __restrict__ hs, unsigned short* __restrict__ y)
{
    const int row = blockIdx.x;
    const int t = threadIdx.x;
    const int nv = CR >> 2;                   // 96 ushort4 per partial row
    float4 val = make_float4(0.f, 0.f, 0.f, 0.f);
    float s = 0.f, ss = 0.f;
    if (t < nv) {
        ushort4 p0 = ((const ushort4*)(h0 + (size_t)row * CR))[t];
        ushort4 p1 = ((const ushort4*)(h1 + (size_t)row * CR))[t];
        float4 bv = ((const float4*)bias)[t];
        val = make_float4(bf2f(p0.x) + bf2f(p1.x) + bv.x,
                          bf2f(p0.y) + bf2f(p1.y) + bv.y,
                          bf2f(p0.z) + bf2f(p1.z) + bv.z,
                          bf2f(p0.w) + bf2f(p1.w) + bv.w);
        ((float4*)(hs + (size_t)row * CR))[t] = val;
        s = val.x + val.y + val.z + val.w;
        ss = val.x * val.x + val.y * val.y + val.z * val.z + val.w * val.w;
    }
    for (int off = 32; off; off >>= 1) {
        s  += __shfl_down(s, off, 64);
        ss += __shfl_down(ss, off, 64);
    }
    __shared__ float rS[2], rSS[2];
    __shared__ float sh_mu, sh_rs;
    int lane = t & 63, w = t >> 6;
    if (lane == 0) { rS[w] = s; rSS[w] = ss; }
    __syncthreads();
    if (t == 0) {
        float S = rS[0] + rS[1];
        float SS = rSS[0] + rSS[1];
        float m = S / CR;
        sh_mu = m;
        sh_rs = rsqrtf(SS / CR - m * m + EPS);
    }
    __syncthreads();
    if (t < nv) {
        float m = sh_mu, r = sh_rs;
        float4 gv = ((const float4*)g)[t];
        float4 bv = ((const float4*)bt)[t];
        uint2 pk;
        pk.x = packbf2((val.x - m) * r * gv.x + bv.x, (val.y - m) * r * gv.y + bv.y);
        pk.y = packbf2((val.z - m) * r * gv.z + bv.z, (val.w - m) * r * gv.w + bv.w);
        *(uint2*)(y + (size_t)row * CR + t * 4) = pk;
    }
}

// ---------------- bf16 MFMA GEMM, 128x128 tile, dbuf LDS + prefetch, split-K ----------------
// MODE 0: bf16 partial out (pitch CR) -> C0 + blockIdx.z*MROWS*CR   (split-K halves)
// MODE 1: qkv epilogue: cols<384 -> bf16 q*SCALE_Q into C0 pitch 768; 384..767 -> bf16 k;
//         cols>=768 -> V^T bf16 into C1 [ch][token] pitch 8192.
template<int KD, int NITER, int MODE>
__global__ __launch_bounds__(256) void gemm_mfma(
    const unsigned short* __restrict__ A,
    const unsigned short* __restrict__ W,
    void* __restrict__ C0, void* __restrict__ C1)
{
    __shared__ unsigned short Asm[2 * 128 * 32];   // 16 KB
    __shared__ unsigned short Bsm[2 * 128 * 32];
    const int t = threadIdx.x;
    const int wave = t >> 6, lane = t & 63;
    const int l15 = lane & 15, quad = lane >> 4;
    const int m0 = blockIdx.y * 128;
    const int n0 = blockIdx.x * 128;
    const int koff = blockIdx.z * (NITER * 32);
    const int wm = (wave & 1) * 64, wn = (wave >> 1) * 64;

    const int srow = lane >> 2;
    const int skq  = (lane & 3) * 8;
    const unsigned short* gA = A + (size_t)(m0 + wave * 32 + srow) * KD + koff + skq;
    const unsigned short* gB = W + (size_t)(n0 + wave * 32 + srow) * KD + koff + skq;
    unsigned short* lA = Asm + wave * 1024;
    unsigned short* lB = Bsm + wave * 1024;

    async_cp16(gA, lA);
    async_cp16(gA + (size_t)16 * KD, lA + 512);
    async_cp16(gB, lB);
    async_cp16(gB + (size_t)16 * KD, lB + 512);

    f32x4 acc[4][4];
#pragma unroll
    for (int i = 0; i < 4; i++)
#pragma unroll
        for (int j = 0; j < 4; j++) acc[i][j] = (f32x4){0.f, 0.f, 0.f, 0.f};

    for (int it = 0; it < NITER; it++) {
        __syncthreads();                     // buf[it&1] staged (vmcnt drained at barrier)
        const int cur = it & 1;
        if (it + 1 < NITER) {
            const int noff = (cur ^ 1) * 4096;
            async_cp16(gA + (it + 1) * 32, lA + noff);
            async_cp16(gA + (size_t)16 * KD + (it + 1) * 32, lA + noff + 512);
            async_cp16(gB + (it + 1) * 32, lB + noff);
            async_cp16(gB + (size_t)16 * KD + (it + 1) * 32, lB + noff + 512);
        }
        const unsigned short* Ab = Asm + cur * 4096;
        const unsigned short* Bb = Bsm + cur * 4096;
        bf16x8 af[4], bfr[4];
#pragma unroll
        for (int i = 0; i < 4; i++)
            af[i] = *(const bf16x8*)(Ab + (wm + i * 16 + l15) * 32 + quad * 8);
#pragma unroll
        for (int j = 0; j < 4; j++)
            bfr[j] = *(const bf16x8*)(Bb + (wn + j * 16 + l15) * 32 + quad * 8);
#pragma unroll
        for (int i = 0; i < 4; i++)
#pragma unroll
            for (int j = 0; j < 4; j++)
                acc[i][j] = __builtin_amdgcn_mfma_f32_16x16x32_bf16(af[i], bfr[j], acc[i][j], 0, 0, 0);
    }

    if constexpr (MODE == 0) {
        unsigned short* C = (unsigned short*)C0 + (size_t)blockIdx.z * MROWS * CR;
#pragma unroll
        for (int i = 0; i < 4; i++)
#pragma unroll
            for (int j = 0; j < 4; j++)
#pragma unroll
                for (int reg = 0; reg < 4; reg++) {
                    int row = m0 + wm + i * 16 + quad * 4 + reg;
                    int col = n0 + wn + j * 16 + l15;
                    C[(size_t)row * CR + col] = f2bf(acc[i][j][reg]);
                }
    } else {
        unsigned short* Cqk = (unsigned short*)C0;    // [token][768] bf16: q(scaled)|k
        unsigned short* Vt  = (unsigned short*)C1;    // [ch][8192] bf16
#pragma unroll
        for (int i = 0; i < 4; i++)
#pragma unroll
            for (int j = 0; j < 4; j++) {
                const int colbase = n0 + wn + j * 16;
                const int token0 = m0 + wm + i * 16 + quad * 4;
                if (colbase < DIM) {
                    const float sc = (colbase < CR) ? SCALE_Q : 1.f;
#pragma unroll
                    for (int reg = 0; reg < 4; reg++)
                        Cqk[(size_t)(token0 + reg) * DIM + colbase + l15] = f2bf(acc[i][j][reg] * sc);
                } else {
                    const int ch = colbase - DIM + l15;
                    uint2 pk;
                    pk.x = packbf2(acc[i][j][0], acc[i][j][1]);
                    pk.y = packbf2(acc[i][j][2], acc[i][j][3]);
                    *(uint2*)(Vt + (size_t)ch * MROWS + token0) = pk;
                }
            }
    }
}

// ---------------- MFMA flash attention: 128-q blocks, S^T core, DBUF K/V staging (R10-proven) ----------------
__global__ __launch_bounds__(256) void attn_mfma(
    const unsigned short* __restrict__ qk,   // [8192][768] bf16: q*SCALE_Q | k
    const unsigned short* __restrict__ vt,   // [384][8192] bf16: V^T
    const float* __restrict__ h, float* __restrict__ out)
{
    const int qt = blockIdx.x;                // 0..7 (128-q tiles)
    const int bh = blockIdx.y;                // 0..95
    const int b = bh / HEADS, head = bh % HEADS;
    const int hc = head * HD;
    const int t = threadIdx.x;
    const int wave = t >> 6, lane = t & 63;
    const int l15 = lane & 15, quad = lane >> 4;
    const int q0 = qt * 128;

    __shared__ unsigned short Ks[2][64 * 40];  // [key][dim] pitch 40, double-buffered
    __shared__ unsigned short Vs[2][32 * 72];  // [ch][key] pitch 72, double-buffered
    __shared__ unsigned short Ps[4][32 * 72];  // wave-private P [q(32)][key] pitch 72
    unsigned short* Pw = Ps[wave];

    bf16x8 qa[2];
#pragma unroll
    for (int qi = 0; qi < 2; qi++)
        qa[qi] = *(const bf16x8*)(qk + (size_t)(b * NN + q0 + wave * 32 + qi * 16 + l15) * DIM
                                  + hc + quad * 8);

    const int rr = t >> 2, seg = t & 3;
    const unsigned short* gK = qk + (size_t)(b * NN + rr) * DIM + CR + hc + seg * 8;
    const int vch = wave * 8 + (lane >> 3), vko = (lane & 7) * 8;
    const unsigned short* gV = vt + (size_t)(hc + vch) * MROWS + b * NN + vko;

    {
        u16x8 k0 = *(const u16x8*)gK;
        u16x8 v0 = *(const u16x8*)gV;
        *(u16x8*)(Ks[0] + rr * 40 + seg * 8) = k0;
        *(u16x8*)(Vs[0] + vch * 72 + vko) = v0;
    }
    u16x8 kreg = *(const u16x8*)(gK + (size_t)64 * DIM);
    u16x8 vreg = *(const u16x8*)(gV + 64);

    f32x4 o[2][2] = {{{0.f,0.f,0.f,0.f},{0.f,0.f,0.f,0.f}},
                     {{0.f,0.f,0.f,0.f},{0.f,0.f,0.f,0.f}}};
    float lpart[2] = {0.f, 0.f};
    __syncthreads();                           // tile 0 visible

    for (int kt = 0; kt < 16; kt++) {
        const int cur = kt & 1;
        const unsigned short* Kc = Ks[cur];
        const unsigned short* Vc = Vs[cur];

        bf16x8 kb[4];
#pragma unroll
        for (int nt = 0; nt < 4; nt++)
            kb[nt] = *(const bf16x8*)(Kc + (nt * 16 + l15) * 40 + quad * 8);

#pragma unroll
        for (int qi = 0; qi < 2; qi++) {
            f32x4 s[4];
#pragma unroll
            for (int nt = 0; nt < 4; nt++) {
                f32x4 z = {0.f, 0.f, 0.f, 0.f};
                s[nt] = __builtin_amdgcn_mfma_f32_16x16x32_bf16(kb[nt], qa[qi], z, 0, 0, 0);
            }
#pragma unroll
            for (int nt = 0; nt < 4; nt++) {
                float e0 = __builtin_amdgcn_exp2f(s[nt][0]);
                float e1 = __builtin_amdgcn_exp2f(s[nt][1]);
                float e2 = __builtin_amdgcn_exp2f(s[nt][2]);
                float e3 = __builtin_amdgcn_exp2f(s[nt][3]);
                lpart[qi] += (e0 + e1) + (e2 + e3);
                uint2 pk;
                pk.x = packbf2(e0, e1);
                pk.y = packbf2(e2, e3);
                *(uint2*)(Pw + (qi * 16 + l15) * 72 + nt * 16 + quad * 4) = pk;
            }
        }

        bf16x8 vb[2][2];
#pragma unroll
        for (int kk = 0; kk < 2; kk++)
#pragma unroll
            for (int nt2 = 0; nt2 < 2; nt2++)
                vb[kk][nt2] = *(const bf16x8*)(Vc + (nt2 * 16 + l15) * 72 + kk * 32 + quad * 8);

#pragma unroll
        for (int qi = 0; qi < 2; qi++)
#pragma unroll
            for (int kk = 0; kk < 2; kk++) {
                bf16x8 pa = *(const bf16x8*)(Pw + (qi * 16 + l15) * 72 + kk * 32 + quad * 8);
#pragma unroll
                for (int nt2 = 0; nt2 < 2; nt2++)
                    o[qi][nt2] = __builtin_amdgcn_mfma_f32_16x16x32_bf16(pa, vb[kk][nt2], o[qi][nt2], 0, 0, 0);
            }

        if (kt < 15) {
            *(u16x8*)(Ks[cur ^ 1] + rr * 40 + seg * 8) = kreg;
            *(u16x8*)(Vs[cur ^ 1] + vch * 72 + vko) = vreg;
            if (kt < 14) {
                kreg = *(const u16x8*)(gK + (size_t)(kt + 2) * 64 * DIM);
                vreg = *(const u16x8*)(gV + (kt + 2) * 64);
            }
        }
        __syncthreads();                       // single barrier per kt
    }

#pragma unroll
    for (int qi = 0; qi < 2; qi++) {
        float l = lpart[qi];
        l += __shfl_xor(l, 16, 64);
        l += __shfl_xor(l, 32, 64);
        const float linv = 1.f / l;
#pragma unroll
        for (int reg = 0; reg < 4; reg++) {
            const float li = __shfl(linv, quad * 4 + reg, 64);
            const size_t row = (size_t)(b * NN + q0 + wave * 32 + qi * 16 + quad * 4 + reg);
#pragma unroll
            for (int nt2 = 0; nt2 < 2; nt2++) {
                size_t idx = row * CR + hc + nt2 * 16 + l15;
                out[idx] = h[idx] + o[qi][nt2][reg] * li;
            }
        }
    }
}

extern "C" void kernel_launch(void* const* d_in, const int* in_sizes, int n_in,
                              void* d_out, int out_size, void* d_ws, size_t ws_size,
                              hipStream_t stream) {
    const float* x      = (const float*)d_in[0];
    const float* ln0_g  = (const float*)d_in[1];
    const float* ln0_b  = (const float*)d_in[2];
    const float* w_proj = (const float*)d_in[3];
    const float* b_proj = (const float*)d_in[4];
    const float* ln1_g  = (const float*)d_in[5];
    const float* ln1_b  = (const float*)d_in[6];
    const float* wq     = (const float*)d_in[7];
    const float* wk     = (const float*)d_in[8];
    const float* wv     = (const float*)d_in[9];
    float* out = (float*)d_out;

    // ws layout: qkb aliases a0 (a0 dead after gemm1 reads it); hp now bf16 (2 x 6.29 MB)
    char* base = (char*)d_ws;
    unsigned short* a0   = (unsigned short*)base;               // 8192*768*2 = 12,582,912
    unsigned short* qkb  = (unsigned short*)base;               // alias
    unsigned short* hp   = (unsigned short*)(base + 12582912);  // 2 x 8192*384*2 = 12,582,912
    float*          hbuf = (float*)(base + 25165824);           // 8192*384*4 = 12,582,912
    unsigned short* yb   = (unsigned short*)(base + 37748736);  // 8192*384*2
    unsigned short* vtb  = (unsigned short*)(base + 44040192);  // 384*8192*2
    unsigned short* wp   = (unsigned short*)(base + 50331648);  // 384*768*2
    unsigned short* wqkv = (unsigned short*)(base + 50921472);  // 1152*384*2

    // 1. a0 = bf16(LN0(x)) + weight casts (wave-per-row LN, partitioned grid)
    ln0_cast<<<2048 + 720, 256, 0, stream>>>(x, ln0_g, ln0_b, a0,
                                             w_proj, wq, wk, wv, wp, wqkv);
    // 2. split-K gemm1: hp[z] = bf16(a0 @ wp^T) (K-half z)
    gemm_mfma<DIM, 12, 0><<<dim3(CR / 128, MROWS / 128, 2), 256, 0, stream>>>(
        a0, wp, hp, nullptr);
    // 3. hsum = hp0+hp1+b_proj; y = bf16(LN1(hsum))
    ln1_sum<<<MROWS, 128, 0, stream>>>(hp, hp + (size_t)MROWS * CR, b_proj,
                                       ln1_g, ln1_b, hbuf, yb);
    // 4. qk (q scaled) + V^T = y @ wqkv^T
    gemm_mfma<CR, 12, 1><<<dim3(1152 / 128, MROWS / 128, 1), 256, 0, stream>>>(
        yb, wqkv, qkb, vtb);
    // 5. out = hsum + attention
    attn_mfma<<<dim3(NN / 128, BB * HEADS), 256, 0, stream>>>(qkb, vtb, hbuf, out);
}

// Round 12
// 157.687 us; speedup vs baseline: 2.8297x; 1.0067x over previous
//
#include <hip/hip_runtime.h>
#include <hip/hip_bf16.h>
#include <math.h>

#define BB 8
#define NN 1024
#define DIM 768
#define HEADS 12
#define CR 384
#define HD 32
#define MROWS (BB*NN)   // 8192
#define EPS 1e-5f
#define SCALE_Q 0.25503486f   // (1/sqrt(32)) * log2(e): P = exp2(s) directly

typedef __attribute__((ext_vector_type(8))) __bf16 bf16x8;
typedef __attribute__((ext_vector_type(8))) unsigned short u16x8;
typedef __attribute__((ext_vector_type(4))) float f32x4;

__device__ __forceinline__ unsigned short f2bf(float f) {
    unsigned int u = __float_as_uint(f);
    u += 0x7fffu + ((u >> 16) & 1u);   // RNE; finite inputs only
    return (unsigned short)(u >> 16);
}

__device__ __forceinline__ unsigned int packbf2(float lo, float hi) {
    __hip_bfloat162 h2 = __float22bfloat162_rn(make_float2(lo, hi));
    unsigned int u; __builtin_memcpy(&u, &h2, sizeof(u));
    return u;
}

__device__ __forceinline__ float bf2f(unsigned short u) {
    unsigned int w = ((unsigned int)u) << 16;
    return __uint_as_float(w);
}

// async global->LDS, 16B/lane; LDS dest = wave-uniform base + lane*16
__device__ __forceinline__ void async_cp16(const unsigned short* g, unsigned short* l) {
    __builtin_amdgcn_global_load_lds(
        (const __attribute__((address_space(1))) unsigned int*)g,
        (__attribute__((address_space(3))) unsigned int*)l, 16, 0, 0);
}

// ---------------- LN0 (wave-per-row) + weight casts (partitioned) ----------------
__global__ __launch_bounds__(256) void ln0_cast(
    const float* __restrict__ x,
    const float* __restrict__ g, const float* __restrict__ bt,
    unsigned short* __restrict__ a0,
    const float* __restrict__ wpf, const float* __restrict__ wq,
    const float* __restrict__ wk, const float* __restrict__ wv,
    unsigned short* __restrict__ wpo, unsigned short* __restrict__ wqkvo)
{
    const int bx = blockIdx.x;
    const int t = threadIdx.x;
    if (bx >= 2048) {   // weight-cast partition
        int i = (bx - 2048) * 256 + t;        // float4 index, covers 184320
        const float* src; unsigned short* dst; int off;
        if (i < 73728) { src = wpf; dst = wpo; off = i; }
        else {
            int j = i - 73728;
            int sel = j / 36864; off = j % 36864;
            src = sel == 0 ? wq : (sel == 1 ? wk : wv);
            dst = wqkvo + (size_t)sel * 147456;
        }
        float4 v = ((const float4*)src)[off];
        uint2 pk; pk.x = packbf2(v.x, v.y); pk.y = packbf2(v.z, v.w);
        ((uint2*)dst)[off] = pk;
        return;
    }
    const int wave = t >> 6, lane = t & 63;
    const int row = bx * 4 + wave;
    const float* a = x + (size_t)row * DIM;
    float4 v[3]; float s = 0.f, ss = 0.f;
#pragma unroll
    for (int c = 0; c < 3; c++) {
        v[c] = ((const float4*)a)[lane + c * 64];
        s  += v[c].x + v[c].y + v[c].z + v[c].w;
        ss += v[c].x * v[c].x + v[c].y * v[c].y + v[c].z * v[c].z + v[c].w * v[c].w;
    }
#pragma unroll
    for (int off = 1; off < 64; off <<= 1) {
        s += __shfl_xor(s, off, 64); ss += __shfl_xor(ss, off, 64);
    }
    const float mu = s / DIM, rs = rsqrtf(ss / DIM - mu * mu + EPS);
#pragma unroll
    for (int c = 0; c < 3; c++) {
        float4 gv = ((const float4*)g)[lane + c * 64];
        float4 bv = ((const float4*)bt)[lane + c * 64];
        uint2 pk;
        pk.x = packbf2((v[c].x - mu) * rs * gv.x + bv.x, (v[c].y - mu) * rs * gv.y + bv.y);
        pk.y = packbf2((v[c].z - mu) * rs * gv.z + bv.z, (v[c].w - mu) * rs * gv.w + bv.w);
        *(uint2*)(a0 + (size_t)row * DIM + (lane + c * 64) * 4) = pk;
    }
}

// ---------------- ln1_sum: hs = bf16(h0)+bf16(h1)+bias (stored bf16); y = bf16(LN1(hs)) ----------------
__global__ __launch_bounds__(128) void ln1_sum(
    const unsigned short* __restrict__ h0, const unsigned short* __restrict__ h1,
    const float* __restrict__ bias,
    const float* __restrict__ g, const float* __restrict__ bt,
    unsigned short* __restrict__ hs, unsigned short* __restrict__ y)
{
    const int row = blockIdx.x;
    const int t = threadIdx.x;
    const int nv = CR >> 2;                   // 96 ushort4 per partial row
    float4 val = make_float4(0.f, 0.f, 0.f, 0.f);
    float s = 0.f, ss = 0.f;
    if (t < nv) {
        ushort4 p0 = ((const ushort4*)(h0 + (size_t)row * CR))[t];
        ushort4 p1 = ((const ushort4*)(h1 + (size_t)row * CR))[t];
        float4 bv = ((const float4*)bias)[t];
        val = make_float4(bf2f(p0.x) + bf2f(p1.x) + bv.x,
                          bf2f(p0.y) + bf2f(p1.y) + bv.y,
                          bf2f(p0.z) + bf2f(p1.z) + bv.z,
                          bf2f(p0.w) + bf2f(p1.w) + bv.w);
        uint2 hk;
        hk.x = packbf2(val.x, val.y);
        hk.y = packbf2(val.z, val.w);
        *(uint2*)(hs + (size_t)row * CR + t * 4) = hk;
        s = val.x + val.y + val.z + val.w;
        ss = val.x * val.x + val.y * val.y + val.z * val.z + val.w * val.w;
    }
    for (int off = 32; off; off >>= 1) {
        s  += __shfl_down(s, off, 64);
        ss += __shfl_down(ss, off, 64);
    }
    __shared__ float rS[2], rSS[2];
    __shared__ float sh_mu, sh_rs;
    int lane = t & 63, w = t >> 6;
    if (lane == 0) { rS[w] = s; rSS[w] = ss; }
    __syncthreads();
    if (t == 0) {
        float S = rS[0] + rS[1];
        float SS = rSS[0] + rSS[1];
        float m = S / CR;
        sh_mu = m;
        sh_rs = rsqrtf(SS / CR - m * m + EPS);
    }
    __syncthreads();
    if (t < nv) {
        float m = sh_mu, r = sh_rs;
        float4 gv = ((const float4*)g)[t];
        float4 bv = ((const float4*)bt)[t];
        uint2 pk;
        pk.x = packbf2((val.x - m) * r * gv.x + bv.x, (val.y - m) * r * gv.y + bv.y);
        pk.y = packbf2((val.z - m) * r * gv.z + bv.z, (val.w - m) * r * gv.w + bv.w);
        *(uint2*)(y + (size_t)row * CR + t * 4) = pk;
    }
}

// ---------------- bf16 MFMA GEMM, 128x128 tile, dbuf LDS + prefetch, split-K (R11-proven) ----------------
// MODE 0: bf16 partial out (pitch CR) -> C0 + blockIdx.z*MROWS*CR
// MODE 1: qkv epilogue: cols<384 -> bf16 q*SCALE_Q into C0 pitch 768; 384..767 -> bf16 k;
//         cols>=768 -> V^T bf16 into C1 [ch][token] pitch 8192.
template<int KD, int NITER, int MODE>
__global__ __launch_bounds__(256) void gemm_mfma(
    const unsigned short* __restrict__ A,
    const unsigned short* __restrict__ W,
    void* __restrict__ C0, void* __restrict__ C1)
{
    __shared__ unsigned short Asm[2 * 128 * 32];   // 16 KB
    __shared__ unsigned short Bsm[2 * 128 * 32];
    const int t = threadIdx.x;
    const int wave = t >> 6, lane = t & 63;
    const int l15 = lane & 15, quad = lane >> 4;
    const int m0 = blockIdx.y * 128;
    const int n0 = blockIdx.x * 128;
    const int koff = blockIdx.z * (NITER * 32);
    const int wm = (wave & 1) * 64, wn = (wave >> 1) * 64;

    const int srow = lane >> 2;
    const int skq  = (lane & 3) * 8;
    const unsigned short* gA = A + (size_t)(m0 + wave * 32 + srow) * KD + koff + skq;
    const unsigned short* gB = W + (size_t)(n0 + wave * 32 + srow) * KD + koff + skq;
    unsigned short* lA = Asm + wave * 1024;
    unsigned short* lB = Bsm + wave * 1024;

    async_cp16(gA, lA);
    async_cp16(gA + (size_t)16 * KD, lA + 512);
    async_cp16(gB, lB);
    async_cp16(gB + (size_t)16 * KD, lB + 512);

    f32x4 acc[4][4];
#pragma unroll
    for (int i = 0; i < 4; i++)
#pragma unroll
        for (int j = 0; j < 4; j++) acc[i][j] = (f32x4){0.f, 0.f, 0.f, 0.f};

    for (int it = 0; it < NITER; it++) {
        __syncthreads();                     // buf[it&1] staged (vmcnt drained at barrier)
        const int cur = it & 1;
        if (it + 1 < NITER) {
            const int noff = (cur ^ 1) * 4096;
            async_cp16(gA + (it + 1) * 32, lA + noff);
            async_cp16(gA + (size_t)16 * KD + (it + 1) * 32, lA + noff + 512);
            async_cp16(gB + (it + 1) * 32, lB + noff);
            async_cp16(gB + (size_t)16 * KD + (it + 1) * 32, lB + noff + 512);
        }
        const unsigned short* Ab = Asm + cur * 4096;
        const unsigned short* Bb = Bsm + cur * 4096;
        bf16x8 af[4], bfr[4];
#pragma unroll
        for (int i = 0; i < 4; i++)
            af[i] = *(const bf16x8*)(Ab + (wm + i * 16 + l15) * 32 + quad * 8);
#pragma unroll
        for (int j = 0; j < 4; j++)
            bfr[j] = *(const bf16x8*)(Bb + (wn + j * 16 + l15) * 32 + quad * 8);
#pragma unroll
        for (int i = 0; i < 4; i++)
#pragma unroll
            for (int j = 0; j < 4; j++)
                acc[i][j] = __builtin_amdgcn_mfma_f32_16x16x32_bf16(af[i], bfr[j], acc[i][j], 0, 0, 0);
    }

    if constexpr (MODE == 0) {
        unsigned short* C = (unsigned short*)C0 + (size_t)blockIdx.z * MROWS * CR;
#pragma unroll
        for (int i = 0; i < 4; i++)
#pragma unroll
            for (int j = 0; j < 4; j++)
#pragma unroll
                for (int reg = 0; reg < 4; reg++) {
                    int row = m0 + wm + i * 16 + quad * 4 + reg;
                    int col = n0 + wn + j * 16 + l15;
                    C[(size_t)row * CR + col] = f2bf(acc[i][j][reg]);
                }
    } else {
        unsigned short* Cqk = (unsigned short*)C0;    // [token][768] bf16: q(scaled)|k
        unsigned short* Vt  = (unsigned short*)C1;    // [ch][8192] bf16
#pragma unroll
        for (int i = 0; i < 4; i++)
#pragma unroll
            for (int j = 0; j < 4; j++) {
                const int colbase = n0 + wn + j * 16;
                const int token0 = m0 + wm + i * 16 + quad * 4;
                if (colbase < DIM) {
                    const float sc = (colbase < CR) ? SCALE_Q : 1.f;
#pragma unroll
                    for (int reg = 0; reg < 4; reg++)
                        Cqk[(size_t)(token0 + reg) * DIM + colbase + l15] = f2bf(acc[i][j][reg] * sc);
                } else {
                    const int ch = colbase - DIM + l15;
                    uint2 pk;
                    pk.x = packbf2(acc[i][j][0], acc[i][j][1]);
                    pk.y = packbf2(acc[i][j][2], acc[i][j][3]);
                    *(uint2*)(Vt + (size_t)ch * MROWS + token0) = pk;
                }
            }
    }
}

// ---------------- MFMA flash attention: 128-q blocks, S^T core, DBUF K/V staging (R10-proven) ----------------
__global__ __launch_bounds__(256) void attn_mfma(
    const unsigned short* __restrict__ qk,   // [8192][768] bf16: q*SCALE_Q | k
    const unsigned short* __restrict__ vt,   // [384][8192] bf16: V^T
    const unsigned short* __restrict__ h,    // [8192][384] bf16 residual
    float* __restrict__ out)
{
    const int qt = blockIdx.x;                // 0..7 (128-q tiles)
    const int bh = blockIdx.y;                // 0..95
    const int b = bh / HEADS, head = bh % HEADS;
    const int hc = head * HD;
    const int t = threadIdx.x;
    const int wave = t >> 6, lane = t & 63;
    const int l15 = lane & 15, quad = lane >> 4;
    const int q0 = qt * 128;

    __shared__ unsigned short Ks[2][64 * 40];  // [key][dim] pitch 40, double-buffered
    __shared__ unsigned short Vs[2][32 * 72];  // [ch][key] pitch 72, double-buffered
    __shared__ unsigned short Ps[4][32 * 72];  // wave-private P [q(32)][key] pitch 72
    unsigned short* Pw = Ps[wave];

    bf16x8 qa[2];
#pragma unroll
    for (int qi = 0; qi < 2; qi++)
        qa[qi] = *(const bf16x8*)(qk + (size_t)(b * NN + q0 + wave * 32 + qi * 16 + l15) * DIM
                                  + hc + quad * 8);

    const int rr = t >> 2, seg = t & 3;
    const unsigned short* gK = qk + (size_t)(b * NN + rr) * DIM + CR + hc + seg * 8;
    const int vch = wave * 8 + (lane >> 3), vko = (lane & 7) * 8;
    const unsigned short* gV = vt + (size_t)(hc + vch) * MROWS + b * NN + vko;

    {
        u16x8 k0 = *(const u16x8*)gK;
        u16x8 v0 = *(const u16x8*)gV;
        *(u16x8*)(Ks[0] + rr * 40 + seg * 8) = k0;
        *(u16x8*)(Vs[0] + vch * 72 + vko) = v0;
    }
    u16x8 kreg = *(const u16x8*)(gK + (size_t)64 * DIM);
    u16x8 vreg = *(const u16x8*)(gV + 64);

    f32x4 o[2][2] = {{{0.f,0.f,0.f,0.f},{0.f,0.f,0.f,0.f}},
                     {{0.f,0.f,0.f,0.f},{0.f,0.f,0.f,0.f}}};
    float lpart[2] = {0.f, 0.f};
    __syncthreads();                           // tile 0 visible

    for (int kt = 0; kt < 16; kt++) {
        const int cur = kt & 1;
        const unsigned short* Kc = Ks[cur];
        const unsigned short* Vc = Vs[cur];

        bf16x8 kb[4];
#pragma unroll
        for (int nt = 0; nt < 4; nt++)
            kb[nt] = *(const bf16x8*)(Kc + (nt * 16 + l15) * 40 + quad * 8);

#pragma unroll
        for (int qi = 0; qi < 2; qi++) {
            f32x4 s[4];
#pragma unroll
            for (int nt = 0; nt < 4; nt++) {
                f32x4 z = {0.f, 0.f, 0.f, 0.f};
                s[nt] = __builtin_amdgcn_mfma_f32_16x16x32_bf16(kb[nt], qa[qi], z, 0, 0, 0);
            }
#pragma unroll
            for (int nt = 0; nt < 4; nt++) {
                float e0 = __builtin_amdgcn_exp2f(s[nt][0]);
                float e1 = __builtin_amdgcn_exp2f(s[nt][1]);
                float e2 = __builtin_amdgcn_exp2f(s[nt][2]);
                float e3 = __builtin_amdgcn_exp2f(s[nt][3]);
                lpart[qi] += (e0 + e1) + (e2 + e3);
                uint2 pk;
                pk.x = packbf2(e0, e1);
                pk.y = packbf2(e2, e3);
                *(uint2*)(Pw + (qi * 16 + l15) * 72 + nt * 16 + quad * 4) = pk;
            }
        }

        bf16x8 vb[2][2];
#pragma unroll
        for (int kk = 0; kk < 2; kk++)
#pragma unroll
            for (int nt2 = 0; nt2 < 2; nt2++)
                vb[kk][nt2] = *(const bf16x8*)(Vc + (nt2 * 16 + l15) * 72 + kk * 32 + quad * 8);

#pragma unroll
        for (int qi = 0; qi < 2; qi++)
#pragma unroll
            for (int kk = 0; kk < 2; kk++) {
                bf16x8 pa = *(const bf16x8*)(Pw + (qi * 16 + l15) * 72 + kk * 32 + quad * 8);
#pragma unroll
                for (int nt2 = 0; nt2 < 2; nt2++)
                    o[qi][nt2] = __builtin_amdgcn_mfma_f32_16x16x32_bf16(pa, vb[kk][nt2], o[qi][nt2], 0, 0, 0);
            }

        if (kt < 15) {
            *(u16x8*)(Ks[cur ^ 1] + rr * 40 + seg * 8) = kreg;
            *(u16x8*)(Vs[cur ^ 1] + vch * 72 + vko) = vreg;
            if (kt < 14) {
                kreg = *(const u16x8*)(gK + (size_t)(kt + 2) * 64 * DIM);
                vreg = *(const u16x8*)(gV + (kt + 2) * 64);
            }
        }
        __syncthreads();                       // single barrier per kt
    }

#pragma unroll
    for (int qi = 0; qi < 2; qi++) {
        float l = lpart[qi];
        l += __shfl_xor(l, 16, 64);
        l += __shfl_xor(l, 32, 64);
        const float linv = 1.f / l;
#pragma unroll
        for (int reg = 0; reg < 4; reg++) {
            const float li = __shfl(linv, quad * 4 + reg, 64);
            const size_t row = (size_t)(b * NN + q0 + wave * 32 + qi * 16 + quad * 4 + reg);
#pragma unroll
            for (int nt2 = 0; nt2 < 2; nt2++) {
                size_t idx = row * CR + hc + nt2 * 16 + l15;
                out[idx] = bf2f(h[idx]) + o[qi][nt2][reg] * li;
            }
        }
    }
}

extern "C" void kernel_launch(void* const* d_in, const int* in_sizes, int n_in,
                              void* d_out, int out_size, void* d_ws, size_t ws_size,
                              hipStream_t stream) {
    const float* x      = (const float*)d_in[0];
    const float* ln0_g  = (const float*)d_in[1];
    const float* ln0_b  = (const float*)d_in[2];
    const float* w_proj = (const float*)d_in[3];
    const float* b_proj = (const float*)d_in[4];
    const float* ln1_g  = (const float*)d_in[5];
    const float* ln1_b  = (const float*)d_in[6];
    const float* wq     = (const float*)d_in[7];
    const float* wk     = (const float*)d_in[8];
    const float* wv     = (const float*)d_in[9];
    float* out = (float*)d_out;

    // ws layout: qkb aliases a0 (a0 dead after gemm1 reads it); hp, hbuf bf16
    char* base = (char*)d_ws;
    unsigned short* a0   = (unsigned short*)base;               // 8192*768*2 = 12,582,912
    unsigned short* qkb  = (unsigned short*)base;               // alias
    unsigned short* hp   = (unsigned short*)(base + 12582912);  // 2 x 8192*384*2 = 12,582,912
    unsigned short* hbuf = (unsigned short*)(base + 25165824);  // 8192*384*2 = 6,291,456
    unsigned short* yb   = (unsigned short*)(base + 31457280);  // 8192*384*2
    unsigned short* vtb  = (unsigned short*)(base + 37748736);  // 384*8192*2
    unsigned short* wp   = (unsigned short*)(base + 44040192);  // 384*768*2
    unsigned short* wqkv = (unsigned short*)(base + 44630016);  // 1152*384*2

    // 1. a0 = bf16(LN0(x)) + weight casts (wave-per-row LN, partitioned grid)
    ln0_cast<<<2048 + 720, 256, 0, stream>>>(x, ln0_g, ln0_b, a0,
                                             w_proj, wq, wk, wv, wp, wqkv);
    // 2. split-K gemm1: hp[z] = bf16(a0 @ wp^T) (K-half z)
    gemm_mfma<DIM, 12, 0><<<dim3(CR / 128, MROWS / 128, 2), 256, 0, stream>>>(
        a0, wp, hp, nullptr);
    // 3. hsum = hp0+hp1+b_proj (bf16); y = bf16(LN1(hsum))
    ln1_sum<<<MROWS, 128, 0, stream>>>(hp, hp + (size_t)MROWS * CR, b_proj,
                                       ln1_g, ln1_b, hbuf, yb);
    // 4. qk (q scaled) + V^T = y @ wqkv^T
    gemm_mfma<CR, 12, 1><<<dim3(1152 / 128, MROWS / 128, 1), 256, 0, stream>>>(
        yb, wqkv, qkb, vtb);
    // 5. out = hsum + attention
    attn_mfma<<<dim3(NN / 128, BB * HEADS), 256, 0, stream>>>(qkb, vtb, hbuf, out);
}